// Round 9
// baseline (225.708 us; speedup 1.0000x reference)
//
#include <hip/hip_runtime.h>
#include <hip/hip_bf16.h>
#include <math.h>

#define T_DIM 2048
#define B_DIM 2
#define E_DIM 1024
#define H_DIM 16
#define HD_DIM 64
#define M_DIM (T_DIM * B_DIM)   // 4096 rows (t*B+b)
#define BH_DIM (B_DIM * H_DIM)  // 32 head-batches

using bf16x8 = __attribute__((ext_vector_type(8))) __bf16;
using u16x8  = __attribute__((ext_vector_type(8))) unsigned short;
using u16x4  = __attribute__((ext_vector_type(4))) unsigned short;
using f32x4  = __attribute__((ext_vector_type(4))) float;

static __device__ __forceinline__ unsigned short f2bf(float f) {
  unsigned u = __builtin_bit_cast(unsigned, f);
  u += 0x7fff + ((u >> 16) & 1);   // RNE
  return (unsigned short)(u >> 16);
}
static __device__ __forceinline__ float bf2f(unsigned short x) {
  return __builtin_bit_cast(float, (unsigned)x << 16);
}

__device__ __forceinline__ void gload_lds16(const void* g, void* l) {
  __builtin_amdgcn_global_load_lds(
      (const __attribute__((address_space(1))) unsigned int*)g,
      (__attribute__((address_space(3))) unsigned int*)l, 16, 0, 0);
}

// ---------------- fp32 -> bf16 cast (both weights, one launch) -------------
__global__ __launch_bounds__(256) void cast2_kernel(
    const float* __restrict__ in1, unsigned short* __restrict__ out1, int n1,
    const float* __restrict__ in2, unsigned short* __restrict__ out2, int n2) {
  int i = blockIdx.x * 256 + threadIdx.x;
  const float* in; unsigned short* out; int idx;
  if (i < n1) { in = in1; out = out1; idx = i; }
  else if (i < n1 + n2) { in = in2; out = out2; idx = i - n1; }
  else return;
  float4 v = ((const float4*)in)[idx];
  ushort4 o;
  o.x = f2bf(v.x); o.y = f2bf(v.y); o.z = f2bf(v.z); o.w = f2bf(v.w);
  ((ushort4*)out)[idx] = o;
}

// ---------------- LayerNorm (row = one block) ----------------
__global__ __launch_bounds__(256) void ln_kernel(
    const float* __restrict__ q, const float* __restrict__ gamma,
    const float* __restrict__ beta, unsigned short* __restrict__ out) {
  int row = blockIdx.x;
  int tid = threadIdx.x;
  const float4* qr = (const float4*)(q + (size_t)row * E_DIM);
  float4 x = qr[tid];
  float s  = x.x + x.y + x.z + x.w;
  float ss = x.x * x.x + x.y * x.y + x.z * x.z + x.w * x.w;
#pragma unroll
  for (int off = 32; off >= 1; off >>= 1) {
    s  += __shfl_xor(s, off, 64);
    ss += __shfl_xor(ss, off, 64);
  }
  __shared__ float red[8];
  int wid = tid >> 6, lane = tid & 63;
  if (lane == 0) { red[wid] = s; red[4 + wid] = ss; }
  __syncthreads();
  s  = red[0] + red[1] + red[2] + red[3];
  ss = red[4] + red[5] + red[6] + red[7];
  float mean = s * (1.0f / E_DIM);
  float var  = ss * (1.0f / E_DIM) - mean * mean;
  float rstd = rsqrtf(var + 1e-5f);
  float4 g4 = ((const float4*)gamma)[tid];
  float4 b4 = ((const float4*)beta)[tid];
  ushort4 o;
  o.x = f2bf((x.x - mean) * rstd * g4.x + b4.x);
  o.y = f2bf((x.y - mean) * rstd * g4.y + b4.y);
  o.z = f2bf((x.z - mean) * rstd * g4.z + b4.z);
  o.w = f2bf((x.w - mean) * rstd * g4.w + b4.w);
  ((ushort4*)(out + (size_t)row * E_DIM))[tid] = o;
}

// ---------------- GEMM: C[M,N] = A[M,K] * Bw[N,K]^T (bf16 in, fp32 acc) ----
// MODE 0: q -> out_q [bh][t][64]; k -> out_pk fragment blobs; v -> out_pv
//         fragment blobs (inverse of the old pack_v gather, fused here)
// MODE 1: out_f = resid + C (fp32)
template <int MODE>
__global__ __launch_bounds__(256) void gemm_bt_kernel(
    const unsigned short* __restrict__ A, const unsigned short* __restrict__ Bw,
    const float* __restrict__ resid, unsigned short* __restrict__ out_q,
    unsigned short* __restrict__ out_pk, unsigned short* __restrict__ out_pv,
    float* __restrict__ out_f, int Kv, int Nv) {
  __shared__ alignas(16) unsigned short lA[128 * 32];
  __shared__ alignas(16) unsigned short lB[128 * 32];
  int tid = threadIdx.x;
  int wid = tid >> 6, lane = tid & 63;
  int wm = wid >> 1, wn = wid & 1;
  int g = lane >> 4, lr = lane & 15;
  int m0 = blockIdx.y * 128, n0 = blockIdx.x * 128;
  f32x4 acc[4][4] = {};

  for (int k0 = 0; k0 < Kv; k0 += 32) {
#pragma unroll
    for (int c = 0; c < 2; ++c) {
      int f16 = c * 256 + tid;
      int row = f16 >> 2, col8 = (f16 & 3) << 3;
      gload_lds16(A  + (size_t)(m0 + row) * Kv + k0 + col8,
                  lA + (size_t)(c * 256 + wid * 64) * 8);
      gload_lds16(Bw + (size_t)(n0 + row) * Kv + k0 + col8,
                  lB + (size_t)(c * 256 + wid * 64) * 8);
    }
    __syncthreads();
    bf16x8 af[4], bfr[4];
#pragma unroll
    for (int r = 0; r < 4; ++r) {
      af[r]  = *(const bf16x8*)(lA + (wm * 64 + r * 16 + lr) * 32 + g * 8);
      bfr[r] = *(const bf16x8*)(lB + (wn * 64 + r * 16 + lr) * 32 + g * 8);
    }
#pragma unroll
    for (int mr = 0; mr < 4; ++mr)
#pragma unroll
      for (int nr = 0; nr < 4; ++nr)
        acc[mr][nr] = __builtin_amdgcn_mfma_f32_16x16x32_bf16(
            af[mr], bfr[nr], acc[mr][nr], 0, 0, 0);
    __syncthreads();
  }

#pragma unroll
  for (int mr = 0; mr < 4; ++mr) {
#pragma unroll
    for (int nr = 0; nr < 4; ++nr) {
#pragma unroll
      for (int r = 0; r < 4; ++r) {
        int grow = m0 + wm * 64 + mr * 16 + g * 4 + r;
        int gcol = n0 + wn * 64 + nr * 16 + lr;
        float v = acc[mr][nr][r];
        if (MODE == 0) {
          int which = gcol >> 10, rem = gcol & 1023;
          int h = rem >> 6, d = rem & 63;
          int t = grow >> 1, b = grow & 1;
          size_t bh = (size_t)(b * H_DIM + h);
          if (which == 0) {
            out_q[(bh * T_DIM + t) * HD_DIM + d] = f2bf(v);
          } else if (which == 1) {
            int tile = t >> 6, trow = t & 63;
            int cf = trow >> 4, ks = d >> 5;
            int plane = ((d >> 3) & 3) * 16 + (trow & 15);
            out_pk[bh * (32 * 8 * 512) +
                   (size_t)((tile * 8) + cf * 2 + ks) * 512 + plane * 8 + (d & 7)]
                = f2bf(v);
          } else {
            // pv[bh][tile][df*2+ks][g2*16+lr2][jh*4+jl],
            // tl = (ks*2+jh)*16 + g2*4 + jl  (inverse of pack_v gather)
            int tile = t >> 6, tl = t & 63;
            int ks2 = tl >> 5, jh = (tl >> 4) & 1, g2 = (tl >> 2) & 3, jl = tl & 3;
            int df = d >> 4, lr2 = d & 15;
            out_pv[bh * (32 * 8 * 512) +
                   (size_t)((tile * 8) + df * 2 + ks2) * 512 +
                   (g2 * 16 + lr2) * 8 + jh * 4 + jl] = f2bf(v);
          }
        } else {
          size_t idx = (size_t)grow * Nv + gcol;
          out_f[idx] = resid[idx] + v;
        }
      }
    }
  }
}

// ---------------- Flash attention v4: KV-split x2, register P -------------
// Fixed-max softmax P = 2^(qk*QS - 8): partials over disjoint KV ranges are
// EXACTLY additive (no rescale). Grid 2048 blocks x 128thr = 4 waves/SIMD.
// Swapped QK^T -> P register-resident (key-order baked into pv layout).
// Single-buffered K regs (prefetch after last use; gap = exp2+PV covers L2
// latency). No LDS, no barriers. Writes unnormalized O^T partials (bf16)
// + S partials (fp32).
__global__ __launch_bounds__(128, 4) void attn_kernel(
    const unsigned short* __restrict__ qb, const unsigned short* __restrict__ pk,
    const unsigned short* __restrict__ pv, unsigned short* __restrict__ pO,
    float* __restrict__ pS) {
  int tid = threadIdx.x;
  int wid = tid >> 6, lane = tid & 63;
  int g = lane >> 4, lr = lane & 15;
  int f = blockIdx.x;                 // 0..2047
  int xcd = f & 7, rest = f >> 3;     // rest: [1:0]=bh_hi, [6:2]=qt, [7]=s
  int bh = xcd + 8 * (rest & 3);      // 4 bh per XCD -> K/V L2-resident
  int qt = (rest >> 2) & 31;
  int s  = rest >> 7;                 // KV half
  const size_t koff = (size_t)bh * T_DIM * HD_DIM;
  const unsigned short* pkp = pk + (size_t)bh * (32 * 8 * 512) +
                              (size_t)s * 16 * 4096 + lane * 8;
  const unsigned short* pvp = pv + (size_t)bh * (32 * 8 * 512) +
                              (size_t)s * 16 * 4096 + lane * 8;

  // Q fragments (32 rows/wave), scale 1/8 * log2(e) folded in
  bf16x8 qf[2][2];
  {
    const float QS = 0.125f * 1.44269504f;
#pragma unroll
    for (int qa = 0; qa < 2; ++qa) {
      int qrow = qt * 64 + wid * 32 + qa * 16 + lr;
#pragma unroll
      for (int ks = 0; ks < 2; ++ks) {
        bf16x8 raw = *(const bf16x8*)(qb + koff + (size_t)qrow * HD_DIM + ks * 32 + g * 8);
#pragma unroll
        for (int j = 0; j < 8; ++j) qf[qa][ks][j] = (__bf16)((float)raw[j] * QS);
      }
    }
  }

  bf16x8 onesf;
#pragma unroll
  for (int j = 0; j < 8; ++j) onesf[j] = (__bf16)1.0f;

  f32x4 accO[2][4] = {};   // accO[qa][df]: O^T[d=df*16+g*4+r][q=lr] partial
  f32x4 accS[2] = {};

  bf16x8 kf[8];
#pragma unroll
  for (int bk = 0; bk < 8; ++bk)
    kf[bk] = *(const bf16x8*)(pkp + (size_t)bk * 512);

  for (int it = 0; it < 16; ++it) {
    bf16x8 vf[8];
#pragma unroll
    for (int bv = 0; bv < 8; ++bv)
      vf[bv] = *(const bf16x8*)(pvp + (size_t)bv * 512);

    f32x4 s4[2][4];
    __builtin_amdgcn_s_setprio(1);
#pragma unroll
    for (int cf = 0; cf < 4; ++cf)
#pragma unroll
      for (int qa = 0; qa < 2; ++qa) {
        f32x4 sv = {-8.0f, -8.0f, -8.0f, -8.0f};
        sv = __builtin_amdgcn_mfma_f32_16x16x32_bf16(kf[cf * 2 + 0], qf[qa][0], sv, 0, 0, 0);
        sv = __builtin_amdgcn_mfma_f32_16x16x32_bf16(kf[cf * 2 + 1], qf[qa][1], sv, 0, 0, 0);
        s4[qa][cf] = sv;
      }
    __builtin_amdgcn_s_setprio(0);

    if (it < 15) {
#pragma unroll
      for (int bk = 0; bk < 8; ++bk)
        kf[bk] = *(const bf16x8*)(pkp + 4096 + (size_t)bk * 512);
    }

    bf16x8 pf[2][2];
#pragma unroll
    for (int qa = 0; qa < 2; ++qa)
#pragma unroll
      for (int j = 0; j < 8; ++j) {
        pf[qa][0][j] = (__bf16)__builtin_amdgcn_exp2f(s4[qa][(j >> 2)][j & 3]);
        pf[qa][1][j] = (__bf16)__builtin_amdgcn_exp2f(s4[qa][2 + (j >> 2)][j & 3]);
      }

    __builtin_amdgcn_s_setprio(1);
#pragma unroll
    for (int ks = 0; ks < 2; ++ks) {
#pragma unroll
      for (int qa = 0; qa < 2; ++qa)
        accS[qa] = __builtin_amdgcn_mfma_f32_16x16x32_bf16(onesf, pf[qa][ks], accS[qa], 0, 0, 0);
#pragma unroll
      for (int df = 0; df < 4; ++df)
#pragma unroll
        for (int qa = 0; qa < 2; ++qa)
          accO[qa][df] = __builtin_amdgcn_mfma_f32_16x16x32_bf16(vf[df * 2 + ks], pf[qa][ks], accO[qa][df], 0, 0, 0);
    }
    __builtin_amdgcn_s_setprio(0);
    pkp += 4096; pvp += 4096;
  }

  // store unnormalized partials: pO[s][bh][qt][d(64)][q(64)] bf16, pS fp32
  unsigned short* pOb = pO + ((size_t)(s * 32 + bh) * 32 + qt) * 4096;
#pragma unroll
  for (int qa = 0; qa < 2; ++qa)
#pragma unroll
    for (int df = 0; df < 4; ++df)
#pragma unroll
      for (int r = 0; r < 4; ++r)
        pOb[(df * 16 + g * 4 + r) * 64 + wid * 32 + qa * 16 + lr] =
            f2bf(accO[qa][df][r]);
  if (g == 0) {
    float* pSb = pS + ((size_t)(s * 32 + bh) * 32 + qt) * 64;
#pragma unroll
    for (int qa = 0; qa < 2; ++qa)
      pSb[wid * 32 + qa * 16 + lr] = accS[qa][0];
  }
}

// ---------------- combine partials: ctx = (O0+O1)/(S0+S1), transpose ------
__global__ __launch_bounds__(256) void reduce_kernel(
    const unsigned short* __restrict__ pO, const float* __restrict__ pS,
    unsigned short* __restrict__ ctx) {
  __shared__ float lo[64][65];
  __shared__ float ls[64];
  int tid = threadIdx.x;
  int bq = blockIdx.x;               // 0..1023
  int bh = bq & 31, qt = bq >> 5;
  int b = bh >> 4, h = bh & 15;
  size_t t0 = ((size_t)bh * 32 + qt) * 4096;
  size_t t1 = ((size_t)(32 + bh) * 32 + qt) * 4096;
  int d = tid >> 2, c = (tid & 3) * 16;
  u16x8 a0 = *(const u16x8*)(pO + t0 + d * 64 + c);
  u16x8 a1 = *(const u16x8*)(pO + t0 + d * 64 + c + 8);
  u16x8 b0 = *(const u16x8*)(pO + t1 + d * 64 + c);
  u16x8 b1 = *(const u16x8*)(pO + t1 + d * 64 + c + 8);
#pragma unroll
  for (int j = 0; j < 8; ++j) {
    lo[d][c + j]     = bf2f(a0[j]) + bf2f(b0[j]);
    lo[d][c + 8 + j] = bf2f(a1[j]) + bf2f(b1[j]);
  }
  if (tid < 64)
    ls[tid] = pS[((size_t)bh * 32 + qt) * 64 + tid] +
              pS[((size_t)(32 + bh) * 32 + qt) * 64 + tid];
  __syncthreads();
  int q = tid >> 2, dc = tid & 3;
  float inv = 1.0f / ls[q];
  u16x8 o0, o1;
#pragma unroll
  for (int k = 0; k < 8; ++k) {
    o0[k] = f2bf(lo[dc * 16 + k][q] * inv);
    o1[k] = f2bf(lo[dc * 16 + 8 + k][q] * inv);
  }
  size_t row = ((size_t)(qt * 64 + q) * B_DIM + b) * E_DIM + h * HD_DIM + dc * 16;
  *(u16x8*)(ctx + row)     = o0;
  *(u16x8*)(ctx + row + 8) = o1;
}

// ---------------- launcher ----------------
extern "C" void kernel_launch(void* const* d_in, const int* in_sizes, int n_in,
                              void* d_out, int out_size, void* d_ws, size_t ws_size,
                              hipStream_t stream) {
  const float* query = (const float*)d_in[0];
  const float* gamma = (const float*)d_in[1];
  const float* beta  = (const float*)d_in[2];
  const float* w_in  = (const float*)d_in[3];
  const float* w_out = (const float*)d_in[4];
  float* out = (float*)d_out;

  unsigned short* ws    = (unsigned short*)d_ws;
  unsigned short* ln    = ws;                                  // 8 MB
  unsigned short* winb  = ln    + (size_t)M_DIM * E_DIM;       // 6 MB
  unsigned short* woutb = winb  + (size_t)3 * E_DIM * E_DIM;   // 2 MB
  unsigned short* qbuf  = woutb + (size_t)E_DIM * E_DIM;       // 8 MB
  unsigned short* ctx   = qbuf  + (size_t)BH_DIM * T_DIM * HD_DIM; // 8 MB
  unsigned short* pk    = ctx   + (size_t)BH_DIM * T_DIM * HD_DIM; // 8 MB
  unsigned short* pv    = pk    + (size_t)BH_DIM * 32 * 8 * 512;   // 8 MB
  unsigned short* pO    = pv    + (size_t)BH_DIM * 32 * 8 * 512;   // 16 MB
  float*          pS    = (float*)(pO + (size_t)2 * BH_DIM * 32 * 4096); // 0.5 MB

  cast2_kernel<<<dim3(4096), dim3(256), 0, stream>>>(
      w_in, winb, 3 * E_DIM * E_DIM / 4, w_out, woutb, E_DIM * E_DIM / 4);
  ln_kernel<<<dim3(M_DIM), dim3(256), 0, stream>>>(query, gamma, beta, ln);
  gemm_bt_kernel<0><<<dim3(3 * E_DIM / 128, M_DIM / 128), dim3(256), 0, stream>>>(
      ln, winb, nullptr, qbuf, pk, pv, nullptr, E_DIM, 3 * E_DIM);
  attn_kernel<<<dim3(2048), dim3(128), 0, stream>>>(qbuf, pk, pv, pO, pS);
  reduce_kernel<<<dim3(1024), dim3(256), 0, stream>>>(pO, pS, ctx);
  gemm_bt_kernel<1><<<dim3(E_DIM / 128, M_DIM / 128), dim3(256), 0, stream>>>(
      ctx, woutb, query, nullptr, nullptr, nullptr, out, E_DIM, E_DIM);
}

// Round 10
// 166.157 us; speedup vs baseline: 1.3584x; 1.3584x over previous
//
#include <hip/hip_runtime.h>
#include <hip/hip_bf16.h>
#include <math.h>

#define T_DIM 2048
#define B_DIM 2
#define E_DIM 1024
#define H_DIM 16
#define HD_DIM 64
#define M_DIM (T_DIM * B_DIM)   // 4096 rows (t*B+b)
#define BH_DIM (B_DIM * H_DIM)  // 32 head-batches

using bf16x8 = __attribute__((ext_vector_type(8))) __bf16;
using u16x8  = __attribute__((ext_vector_type(8))) unsigned short;
using u16x4  = __attribute__((ext_vector_type(4))) unsigned short;
using f32x4  = __attribute__((ext_vector_type(4))) float;

static __device__ __forceinline__ unsigned short f2bf(float f) {
  unsigned u = __builtin_bit_cast(unsigned, f);
  u += 0x7fff + ((u >> 16) & 1);   // RNE
  return (unsigned short)(u >> 16);
}
static __device__ __forceinline__ float bf2f(unsigned short x) {
  return __builtin_bit_cast(float, (unsigned)x << 16);
}

__device__ __forceinline__ void gload_lds16(const void* g, void* l) {
  __builtin_amdgcn_global_load_lds(
      (const __attribute__((address_space(1))) unsigned int*)g,
      (__attribute__((address_space(3))) unsigned int*)l, 16, 0, 0);
}

// ---------------- fp32 -> bf16 cast (both weights, one launch) -------------
__global__ __launch_bounds__(256) void cast2_kernel(
    const float* __restrict__ in1, unsigned short* __restrict__ out1, int n1,
    const float* __restrict__ in2, unsigned short* __restrict__ out2, int n2) {
  int i = blockIdx.x * 256 + threadIdx.x;
  const float* in; unsigned short* out; int idx;
  if (i < n1) { in = in1; out = out1; idx = i; }
  else if (i < n1 + n2) { in = in2; out = out2; idx = i - n1; }
  else return;
  float4 v = ((const float4*)in)[idx];
  ushort4 o;
  o.x = f2bf(v.x); o.y = f2bf(v.y); o.z = f2bf(v.z); o.w = f2bf(v.w);
  ((ushort4*)out)[idx] = o;
}

// ---------------- LayerNorm (row = one block) ----------------
__global__ __launch_bounds__(256) void ln_kernel(
    const float* __restrict__ q, const float* __restrict__ gamma,
    const float* __restrict__ beta, unsigned short* __restrict__ out) {
  int row = blockIdx.x;
  int tid = threadIdx.x;
  const float4* qr = (const float4*)(q + (size_t)row * E_DIM);
  float4 x = qr[tid];
  float s  = x.x + x.y + x.z + x.w;
  float ss = x.x * x.x + x.y * x.y + x.z * x.z + x.w * x.w;
#pragma unroll
  for (int off = 32; off >= 1; off >>= 1) {
    s  += __shfl_xor(s, off, 64);
    ss += __shfl_xor(ss, off, 64);
  }
  __shared__ float red[8];
  int wid = tid >> 6, lane = tid & 63;
  if (lane == 0) { red[wid] = s; red[4 + wid] = ss; }
  __syncthreads();
  s  = red[0] + red[1] + red[2] + red[3];
  ss = red[4] + red[5] + red[6] + red[7];
  float mean = s * (1.0f / E_DIM);
  float var  = ss * (1.0f / E_DIM) - mean * mean;
  float rstd = rsqrtf(var + 1e-5f);
  float4 g4 = ((const float4*)gamma)[tid];
  float4 b4 = ((const float4*)beta)[tid];
  ushort4 o;
  o.x = f2bf((x.x - mean) * rstd * g4.x + b4.x);
  o.y = f2bf((x.y - mean) * rstd * g4.y + b4.y);
  o.z = f2bf((x.z - mean) * rstd * g4.z + b4.z);
  o.w = f2bf((x.w - mean) * rstd * g4.w + b4.w);
  ((ushort4*)(out + (size_t)row * E_DIM))[tid] = o;
}

// ---------------- GEMM: C[M,N] = A[M,K] * Bw[N,K]^T (bf16 in, fp32 acc) ----
// MODE 0: q -> out_q [bh][t][64]; k -> out_pk fragment blobs; v -> out_pv
//         fragment blobs (attn's swapped-QK register-P key order)
// MODE 1: out_f = resid + C (fp32)
template <int MODE>
__global__ __launch_bounds__(256) void gemm_bt_kernel(
    const unsigned short* __restrict__ A, const unsigned short* __restrict__ Bw,
    const float* __restrict__ resid, unsigned short* __restrict__ out_q,
    unsigned short* __restrict__ out_pk, unsigned short* __restrict__ out_pv,
    float* __restrict__ out_f, int Kv, int Nv) {
  __shared__ alignas(16) unsigned short lA[128 * 32];
  __shared__ alignas(16) unsigned short lB[128 * 32];
  int tid = threadIdx.x;
  int wid = tid >> 6, lane = tid & 63;
  int wm = wid >> 1, wn = wid & 1;
  int g = lane >> 4, lr = lane & 15;
  int m0 = blockIdx.y * 128, n0 = blockIdx.x * 128;
  f32x4 acc[4][4] = {};

  for (int k0 = 0; k0 < Kv; k0 += 32) {
#pragma unroll
    for (int c = 0; c < 2; ++c) {
      int f16 = c * 256 + tid;
      int row = f16 >> 2, col8 = (f16 & 3) << 3;
      gload_lds16(A  + (size_t)(m0 + row) * Kv + k0 + col8,
                  lA + (size_t)(c * 256 + wid * 64) * 8);
      gload_lds16(Bw + (size_t)(n0 + row) * Kv + k0 + col8,
                  lB + (size_t)(c * 256 + wid * 64) * 8);
    }
    __syncthreads();
    bf16x8 af[4], bfr[4];
#pragma unroll
    for (int r = 0; r < 4; ++r) {
      af[r]  = *(const bf16x8*)(lA + (wm * 64 + r * 16 + lr) * 32 + g * 8);
      bfr[r] = *(const bf16x8*)(lB + (wn * 64 + r * 16 + lr) * 32 + g * 8);
    }
#pragma unroll
    for (int mr = 0; mr < 4; ++mr)
#pragma unroll
      for (int nr = 0; nr < 4; ++nr)
        acc[mr][nr] = __builtin_amdgcn_mfma_f32_16x16x32_bf16(
            af[mr], bfr[nr], acc[mr][nr], 0, 0, 0);
    __syncthreads();
  }

#pragma unroll
  for (int mr = 0; mr < 4; ++mr) {
#pragma unroll
    for (int nr = 0; nr < 4; ++nr) {
#pragma unroll
      for (int r = 0; r < 4; ++r) {
        int grow = m0 + wm * 64 + mr * 16 + g * 4 + r;
        int gcol = n0 + wn * 64 + nr * 16 + lr;
        float v = acc[mr][nr][r];
        if (MODE == 0) {
          int which = gcol >> 10, rem = gcol & 1023;
          int h = rem >> 6, d = rem & 63;
          int t = grow >> 1, b = grow & 1;
          size_t bh = (size_t)(b * H_DIM + h);
          if (which == 0) {
            out_q[(bh * T_DIM + t) * HD_DIM + d] = f2bf(v);
          } else if (which == 1) {
            int tile = t >> 6, trow = t & 63;
            int cf = trow >> 4, ks = d >> 5;
            int plane = ((d >> 3) & 3) * 16 + (trow & 15);
            out_pk[bh * (32 * 8 * 512) +
                   (size_t)((tile * 8) + cf * 2 + ks) * 512 + plane * 8 + (d & 7)]
                = f2bf(v);
          } else {
            // pv[bh][tile][df*2+ks][g2*16+lr2][jh*4+jl],
            // tl = (ks*2+jh)*16 + g2*4 + jl
            int tile = t >> 6, tl = t & 63;
            int ks2 = tl >> 5, jh = (tl >> 4) & 1, g2 = (tl >> 2) & 3, jl = tl & 3;
            int df = d >> 4, lr2 = d & 15;
            out_pv[bh * (32 * 8 * 512) +
                   (size_t)((tile * 8) + df * 2 + ks2) * 512 +
                   (g2 * 16 + lr2) * 8 + jh * 4 + jl] = f2bf(v);
          }
        } else {
          size_t idx = (size_t)grow * Nv + gcol;
          out_f[idx] = resid[idx] + v;
        }
      }
    }
  }
}

// ---------------- Flash attention v5: KV-split x2, 16 q-rows/wave ---------
// Fixed-max softmax P = 2^(qk*QS - 8): disjoint-KV partials EXACTLY additive.
// Grid 4096 blocks x 128 thr = 8192 waves (8/SIMD supply); per-wave state
// ~105 VGPR (16 q-rows + K/V TIME-SHARED in one reg block) -> 4 waves/SIMD
// naturally, NO min-waves clause (r9's forced-spill lesson).
// Swapped QK^T -> P register-resident. No LDS, no barriers.
__global__ __launch_bounds__(128) void attn_kernel(
    const unsigned short* __restrict__ qb, const unsigned short* __restrict__ pk,
    const unsigned short* __restrict__ pv, unsigned short* __restrict__ pO,
    float* __restrict__ pS) {
  int tid = threadIdx.x;
  int wid = tid >> 6, lane = tid & 63;
  int g = lane >> 4, lr = lane & 15;
  int f = blockIdx.x;                 // 0..4095
  int xcd = f & 7, rest = f >> 3;     // rest: [1:0]=bh_hi, [7:2]=qt, [8]=s
  int bh = xcd + 8 * (rest & 3);      // 4 bh per XCD -> K/V L2-resident
  int qt = (rest >> 2) & 63;          // 32-row q-tile
  int s  = rest >> 8;                 // KV half
  const size_t koff = (size_t)bh * T_DIM * HD_DIM;
  const unsigned short* pkp = pk + (size_t)bh * (32 * 8 * 512) +
                              (size_t)s * 16 * 4096 + lane * 8;
  const unsigned short* pvp = pv + (size_t)bh * (32 * 8 * 512) +
                              (size_t)s * 16 * 4096 + lane * 8;

  // Q fragments (16 rows/wave), scale 1/8 * log2(e) folded in
  bf16x8 qf[2];
  {
    const float QS = 0.125f * 1.44269504f;
    int qrow = qt * 32 + wid * 16 + lr;
#pragma unroll
    for (int ks = 0; ks < 2; ++ks) {
      bf16x8 raw = *(const bf16x8*)(qb + koff + (size_t)qrow * HD_DIM + ks * 32 + g * 8);
#pragma unroll
      for (int j = 0; j < 8; ++j) qf[ks][j] = (__bf16)((float)raw[j] * QS);
    }
  }

  bf16x8 onesf;
#pragma unroll
  for (int j = 0; j < 8; ++j) onesf[j] = (__bf16)1.0f;

  f32x4 accO[4] = {};   // accO[df]: O^T[d=df*16+g*4+r][q=lr] partial
  f32x4 accS = {};

  for (int it = 0; it < 16; ++it) {
    bf16x8 kv[8];                       // time-shared K then V
#pragma unroll
    for (int bk = 0; bk < 8; ++bk)
      kv[bk] = *(const bf16x8*)(pkp + ((size_t)it * 8 + bk) * 512);

    f32x4 s4[4];
    __builtin_amdgcn_s_setprio(1);
#pragma unroll
    for (int cf = 0; cf < 4; ++cf) {
      f32x4 sv = {-8.0f, -8.0f, -8.0f, -8.0f};
      sv = __builtin_amdgcn_mfma_f32_16x16x32_bf16(kv[cf * 2 + 0], qf[0], sv, 0, 0, 0);
      sv = __builtin_amdgcn_mfma_f32_16x16x32_bf16(kv[cf * 2 + 1], qf[1], sv, 0, 0, 0);
      s4[cf] = sv;
    }
    __builtin_amdgcn_s_setprio(0);

#pragma unroll
    for (int bv = 0; bv < 8; ++bv)      // overwrite with V (K dead)
      kv[bv] = *(const bf16x8*)(pvp + ((size_t)it * 8 + bv) * 512);

    bf16x8 pf[2];
#pragma unroll
    for (int j = 0; j < 8; ++j) {
      pf[0][j] = (__bf16)__builtin_amdgcn_exp2f(s4[(j >> 2)][j & 3]);
      pf[1][j] = (__bf16)__builtin_amdgcn_exp2f(s4[2 + (j >> 2)][j & 3]);
    }

    __builtin_amdgcn_s_setprio(1);
#pragma unroll
    for (int ks = 0; ks < 2; ++ks) {
      accS = __builtin_amdgcn_mfma_f32_16x16x32_bf16(onesf, pf[ks], accS, 0, 0, 0);
#pragma unroll
      for (int df = 0; df < 4; ++df)
        accO[df] = __builtin_amdgcn_mfma_f32_16x16x32_bf16(kv[df * 2 + ks], pf[ks], accO[df], 0, 0, 0);
    }
    __builtin_amdgcn_s_setprio(0);
  }

  // store unnormalized partials: pO[s][bh][qt][d(64)][q(32)] bf16, pS fp32
  unsigned short* pOb = pO + ((size_t)(s * 32 + bh) * 64 + qt) * 2048;
#pragma unroll
  for (int df = 0; df < 4; ++df)
#pragma unroll
    for (int r = 0; r < 4; ++r)
      pOb[(df * 16 + g * 4 + r) * 32 + wid * 16 + lr] = f2bf(accO[df][r]);
  if (g == 0) {
    float* pSb = pS + ((size_t)(s * 32 + bh) * 64 + qt) * 32;
    pSb[wid * 16 + lr] = accS[0];
  }
}

// ---------------- combine partials: ctx = (O0+O1)/(S0+S1), transpose ------
__global__ __launch_bounds__(256) void reduce_kernel(
    const unsigned short* __restrict__ pO, const float* __restrict__ pS,
    unsigned short* __restrict__ ctx) {
  __shared__ float lo[64][65];
  __shared__ float ls[64];
  int tid = threadIdx.x;
  int bq = blockIdx.x;               // 0..1023
  int bh = bq & 31, qg = bq >> 5;    // qg: 64-row group
  int b = bh >> 4, h = bh & 15;
  size_t t0 = ((size_t)bh * 64 + qg * 2) * 2048;          // s=0, two 32-row tiles
  size_t t1 = ((size_t)(32 + bh) * 64 + qg * 2) * 2048;   // s=1
  int d = tid >> 2, c = (tid & 3) * 16;
  int sel = c >> 5, qb0 = c & 31;
  size_t off = (size_t)sel * 2048 + d * 32 + qb0;
  u16x8 a0 = *(const u16x8*)(pO + t0 + off);
  u16x8 a1 = *(const u16x8*)(pO + t0 + off + 8);
  u16x8 b0 = *(const u16x8*)(pO + t1 + off);
  u16x8 b1 = *(const u16x8*)(pO + t1 + off + 8);
#pragma unroll
  for (int j = 0; j < 8; ++j) {
    lo[d][c + j]     = bf2f(a0[j]) + bf2f(b0[j]);
    lo[d][c + 8 + j] = bf2f(a1[j]) + bf2f(b1[j]);
  }
  if (tid < 64) {
    int qt2 = qg * 2 + (tid >> 5), qi = tid & 31;
    ls[tid] = pS[((size_t)bh * 64 + qt2) * 32 + qi] +
              pS[((size_t)(32 + bh) * 64 + qt2) * 32 + qi];
  }
  __syncthreads();
  int q = tid >> 2, dc = tid & 3;
  float inv = 1.0f / ls[q];
  u16x8 o0, o1;
#pragma unroll
  for (int k = 0; k < 8; ++k) {
    o0[k] = f2bf(lo[dc * 16 + k][q] * inv);
    o1[k] = f2bf(lo[dc * 16 + 8 + k][q] * inv);
  }
  size_t row = ((size_t)(qg * 64 + q) * B_DIM + b) * E_DIM + h * HD_DIM + dc * 16;
  *(u16x8*)(ctx + row)     = o0;
  *(u16x8*)(ctx + row + 8) = o1;
}

// ---------------- launcher ----------------
extern "C" void kernel_launch(void* const* d_in, const int* in_sizes, int n_in,
                              void* d_out, int out_size, void* d_ws, size_t ws_size,
                              hipStream_t stream) {
  const float* query = (const float*)d_in[0];
  const float* gamma = (const float*)d_in[1];
  const float* beta  = (const float*)d_in[2];
  const float* w_in  = (const float*)d_in[3];
  const float* w_out = (const float*)d_in[4];
  float* out = (float*)d_out;

  unsigned short* ws    = (unsigned short*)d_ws;
  unsigned short* ln    = ws;                                  // 8 MB
  unsigned short* winb  = ln    + (size_t)M_DIM * E_DIM;       // 6 MB
  unsigned short* woutb = winb  + (size_t)3 * E_DIM * E_DIM;   // 2 MB
  unsigned short* qbuf  = woutb + (size_t)E_DIM * E_DIM;       // 8 MB
  unsigned short* ctx   = qbuf  + (size_t)BH_DIM * T_DIM * HD_DIM; // 8 MB
  unsigned short* pk    = ctx   + (size_t)BH_DIM * T_DIM * HD_DIM; // 8 MB
  unsigned short* pv    = pk    + (size_t)BH_DIM * 32 * 8 * 512;   // 8 MB
  unsigned short* pO    = pv    + (size_t)BH_DIM * 32 * 8 * 512;   // 16 MB
  float*          pS    = (float*)(pO + (size_t)2 * BH_DIM * 64 * 2048); // 0.5 MB

  cast2_kernel<<<dim3(4096), dim3(256), 0, stream>>>(
      w_in, winb, 3 * E_DIM * E_DIM / 4, w_out, woutb, E_DIM * E_DIM / 4);
  ln_kernel<<<dim3(M_DIM), dim3(256), 0, stream>>>(query, gamma, beta, ln);
  gemm_bt_kernel<0><<<dim3(3 * E_DIM / 128, M_DIM / 128), dim3(256), 0, stream>>>(
      ln, winb, nullptr, qbuf, pk, pv, nullptr, E_DIM, 3 * E_DIM);
  attn_kernel<<<dim3(4096), dim3(128), 0, stream>>>(qbuf, pk, pv, pO, pS);
  reduce_kernel<<<dim3(1024), dim3(256), 0, stream>>>(pO, pS, ctx);
  gemm_bt_kernel<1><<<dim3(E_DIM / 128, M_DIM / 128), dim3(256), 0, stream>>>(
      ctx, woutb, query, nullptr, nullptr, nullptr, out, E_DIM, E_DIM);
}

// Round 11
// 122.281 us; speedup vs baseline: 1.8458x; 1.3588x over previous
//
#include <hip/hip_runtime.h>
#include <hip/hip_bf16.h>
#include <math.h>

#define T_DIM 2048
#define B_DIM 2
#define E_DIM 1024
#define H_DIM 16
#define HD_DIM 64
#define M_DIM (T_DIM * B_DIM)   // 4096 rows (t*B+b)
#define BH_DIM (B_DIM * H_DIM)  // 32 head-batches

using bf16x8 = __attribute__((ext_vector_type(8))) __bf16;
using u16x8  = __attribute__((ext_vector_type(8))) unsigned short;
using u16x4  = __attribute__((ext_vector_type(4))) unsigned short;
using f32x4  = __attribute__((ext_vector_type(4))) float;

static __device__ __forceinline__ unsigned short f2bf(float f) {
  unsigned u = __builtin_bit_cast(unsigned, f);
  u += 0x7fff + ((u >> 16) & 1);   // RNE
  return (unsigned short)(u >> 16);
}

__device__ __forceinline__ void gload_lds16(const void* g, void* l) {
  __builtin_amdgcn_global_load_lds(
      (const __attribute__((address_space(1))) unsigned int*)g,
      (__attribute__((address_space(3))) unsigned int*)l, 16, 0, 0);
}

// ---------------- fp32 -> bf16 cast (both weights, one launch) -------------
__global__ __launch_bounds__(256) void cast2_kernel(
    const float* __restrict__ in1, unsigned short* __restrict__ out1, int n1,
    const float* __restrict__ in2, unsigned short* __restrict__ out2, int n2) {
  int i = blockIdx.x * 256 + threadIdx.x;
  const float* in; unsigned short* out; int idx;
  if (i < n1) { in = in1; out = out1; idx = i; }
  else if (i < n1 + n2) { in = in2; out = out2; idx = i - n1; }
  else return;
  float4 v = ((const float4*)in)[idx];
  ushort4 o;
  o.x = f2bf(v.x); o.y = f2bf(v.y); o.z = f2bf(v.z); o.w = f2bf(v.w);
  ((ushort4*)out)[idx] = o;
}

// ---------------- LayerNorm (row = one block) ----------------
__global__ __launch_bounds__(256) void ln_kernel(
    const float* __restrict__ q, const float* __restrict__ gamma,
    const float* __restrict__ beta, unsigned short* __restrict__ out) {
  int row = blockIdx.x;
  int tid = threadIdx.x;
  const float4* qr = (const float4*)(q + (size_t)row * E_DIM);
  float4 x = qr[tid];
  float s  = x.x + x.y + x.z + x.w;
  float ss = x.x * x.x + x.y * x.y + x.z * x.z + x.w * x.w;
#pragma unroll
  for (int off = 32; off >= 1; off >>= 1) {
    s  += __shfl_xor(s, off, 64);
    ss += __shfl_xor(ss, off, 64);
  }
  __shared__ float red[8];
  int wid = tid >> 6, lane = tid & 63;
  if (lane == 0) { red[wid] = s; red[4 + wid] = ss; }
  __syncthreads();
  s  = red[0] + red[1] + red[2] + red[3];
  ss = red[4] + red[5] + red[6] + red[7];
  float mean = s * (1.0f / E_DIM);
  float var  = ss * (1.0f / E_DIM) - mean * mean;
  float rstd = rsqrtf(var + 1e-5f);
  float4 g4 = ((const float4*)gamma)[tid];
  float4 b4 = ((const float4*)beta)[tid];
  ushort4 o;
  o.x = f2bf((x.x - mean) * rstd * g4.x + b4.x);
  o.y = f2bf((x.y - mean) * rstd * g4.y + b4.y);
  o.z = f2bf((x.z - mean) * rstd * g4.z + b4.z);
  o.w = f2bf((x.w - mean) * rstd * g4.w + b4.w);
  ((ushort4*)(out + (size_t)row * E_DIM))[tid] = o;
}

// ---------------- GEMM0: qkv = ln @ Win^T, scatter to [3][bh][t][64] ------
__global__ __launch_bounds__(256) void gemm0_kernel(
    const unsigned short* __restrict__ A, const unsigned short* __restrict__ Bw,
    unsigned short* __restrict__ out_qkv) {
  __shared__ alignas(16) unsigned short lA[128 * 32];
  __shared__ alignas(16) unsigned short lB[128 * 32];
  int tid = threadIdx.x;
  int wid = tid >> 6, lane = tid & 63;
  int wm = wid >> 1, wn = wid & 1;
  int g = lane >> 4, lr = lane & 15;
  int m0 = blockIdx.y * 128, n0 = blockIdx.x * 128;
  f32x4 acc[4][4] = {};

  for (int k0 = 0; k0 < E_DIM; k0 += 32) {
#pragma unroll
    for (int c = 0; c < 2; ++c) {
      int f16 = c * 256 + tid;
      int row = f16 >> 2, col8 = (f16 & 3) << 3;
      gload_lds16(A  + (size_t)(m0 + row) * E_DIM + k0 + col8,
                  lA + (size_t)(c * 256 + wid * 64) * 8);
      gload_lds16(Bw + (size_t)(n0 + row) * E_DIM + k0 + col8,
                  lB + (size_t)(c * 256 + wid * 64) * 8);
    }
    __syncthreads();
    bf16x8 af[4], bfr[4];
#pragma unroll
    for (int r = 0; r < 4; ++r) {
      af[r]  = *(const bf16x8*)(lA + (wm * 64 + r * 16 + lr) * 32 + g * 8);
      bfr[r] = *(const bf16x8*)(lB + (wn * 64 + r * 16 + lr) * 32 + g * 8);
    }
#pragma unroll
    for (int mr = 0; mr < 4; ++mr)
#pragma unroll
      for (int nr = 0; nr < 4; ++nr)
        acc[mr][nr] = __builtin_amdgcn_mfma_f32_16x16x32_bf16(
            af[mr], bfr[nr], acc[mr][nr], 0, 0, 0);
    __syncthreads();
  }

#pragma unroll
  for (int mr = 0; mr < 4; ++mr) {
#pragma unroll
    for (int nr = 0; nr < 4; ++nr) {
#pragma unroll
      for (int r = 0; r < 4; ++r) {
        int grow = m0 + wm * 64 + mr * 16 + g * 4 + r;
        int gcol = n0 + wn * 64 + nr * 16 + lr;
        int which = gcol >> 10, rem = gcol & 1023;
        int h = rem >> 6, d = rem & 63;
        int t = grow >> 1, b = grow & 1;
        out_qkv[(size_t)which * (BH_DIM * T_DIM * HD_DIM) +
                ((size_t)(b * H_DIM + h) * T_DIM + t) * HD_DIM + d] =
            f2bf(acc[mr][nr][r]);
      }
    }
  }
}

// ---------------- GEMM1: out = resid + ctx @ Wout^T (128x64 tile) --------
__global__ __launch_bounds__(256) void gemm1_kernel(
    const unsigned short* __restrict__ A, const unsigned short* __restrict__ Bw,
    const float* __restrict__ resid, float* __restrict__ out) {
  __shared__ alignas(16) unsigned short lA[128 * 32];
  __shared__ alignas(16) unsigned short lB[64 * 32];
  int tid = threadIdx.x;
  int wid = tid >> 6, lane = tid & 63;
  int g = lane >> 4, lr = lane & 15;
  int m0 = blockIdx.y * 128, n0 = blockIdx.x * 64;
  f32x4 acc[2][4] = {};

  for (int k0 = 0; k0 < E_DIM; k0 += 32) {
#pragma unroll
    for (int c = 0; c < 2; ++c) {
      int f16 = c * 256 + tid;
      int row = f16 >> 2, col8 = (f16 & 3) << 3;
      gload_lds16(A + (size_t)(m0 + row) * E_DIM + k0 + col8,
                  lA + (size_t)(c * 256 + wid * 64) * 8);
    }
    {
      int row = tid >> 2, col8 = (tid & 3) << 3;
      gload_lds16(Bw + (size_t)(n0 + row) * E_DIM + k0 + col8,
                  lB + (size_t)(wid * 64) * 8);
    }
    __syncthreads();
    bf16x8 af[2], bfr[4];
#pragma unroll
    for (int r = 0; r < 2; ++r)
      af[r] = *(const bf16x8*)(lA + (wid * 32 + r * 16 + lr) * 32 + g * 8);
#pragma unroll
    for (int r = 0; r < 4; ++r)
      bfr[r] = *(const bf16x8*)(lB + (r * 16 + lr) * 32 + g * 8);
#pragma unroll
    for (int mr = 0; mr < 2; ++mr)
#pragma unroll
      for (int nr = 0; nr < 4; ++nr)
        acc[mr][nr] = __builtin_amdgcn_mfma_f32_16x16x32_bf16(
            af[mr], bfr[nr], acc[mr][nr], 0, 0, 0);
    __syncthreads();
  }

#pragma unroll
  for (int mr = 0; mr < 2; ++mr) {
#pragma unroll
    for (int nr = 0; nr < 4; ++nr) {
#pragma unroll
      for (int r = 0; r < 4; ++r) {
        int grow = m0 + wid * 32 + mr * 16 + g * 4 + r;
        int gcol = n0 + nr * 16 + lr;
        size_t idx = (size_t)grow * E_DIM + gcol;
        out[idx] = resid[idx] + acc[mr][nr][r];
      }
    }
  }
}

// ---------------- V transpose: [bh][t][d] -> [bh][d][perm(t)] -------------
// Within each 64-t tile, output column p holds logical key
//   tl(p) = (ks*2 + (j>>2))*16 + g*4 + (j&3)  with  ks=p>>5, g=(p>>3)&3, j=p&7
// chosen so PV's B-operand equals the register-resident P after swapped QK^T.
__global__ __launch_bounds__(256) void transpose_v_kernel(
    const unsigned short* __restrict__ vb, unsigned short* __restrict__ vt) {
  __shared__ alignas(16) unsigned short tl[64 * 72];
  int tid = threadIdx.x;
  int bh = blockIdx.y, t0 = blockIdx.x * 64;
  const unsigned short* src = vb + ((size_t)bh * T_DIM + t0) * HD_DIM;
#pragma unroll
  for (int e = 0; e < 2; ++e) {
    int i8 = e * 256 + tid;
    int r = i8 >> 3;                  // t-row 0..63
    int c = (i8 & 7) * 8;             // d chunk
    int hsh = (r ^ (r >> 3)) & 7;
    bf16x8 v = *(const bf16x8*)(src + (size_t)r * HD_DIM + c);
    *(bf16x8*)(tl + r * 72 + (c ^ (hsh << 3))) = v;
  }
  __syncthreads();
  unsigned short* dst = vt + (size_t)bh * HD_DIM * T_DIM + t0;
#pragma unroll
  for (int e = 0; e < 2; ++e) {
    int i8 = e * 256 + tid;
    int d = i8 >> 3;                  // d-row 0..63
    int tc = (i8 & 7) * 8;            // phys t chunk
    u16x8 o;
#pragma unroll
    for (int j = 0; j < 8; ++j) {
      int p = tc + j;                 // phys position
      int ks = p >> 5, gg = (p >> 3) & 3, jl = p & 7;
      int r = (ks * 2 + (jl >> 2)) * 16 + gg * 4 + (jl & 3);
      int hsh = (r ^ (r >> 3)) & 7;
      o[j] = tl[r * 72 + (d ^ (hsh << 3))];
    }
    *(u16x8*)(dst + (size_t)d * T_DIM + tc) = o;
  }
}

// ---------------- Flash attention v6: r6 structure + register P -----------
// LDS K/V (3-buffer, ONE barrier/tile), swapped QK^T (A=K, B=Q) so each lane
// holds P[q=lr][key cf*16+g*4+r] in registers; PV: O^T = mfma(V^T, P) with
// the key-permutation baked into transpose_v. Row-sum via mfma(ones, P).
// No P LDS round-trip. XCD-swizzled 1D grid: 4 bh per XCD (K/V L2-resident).
__global__ __launch_bounds__(256) void attn_kernel(
    const unsigned short* __restrict__ qb, const unsigned short* __restrict__ kb,
    const unsigned short* __restrict__ vt, unsigned short* __restrict__ ctx) {
  __shared__ alignas(16) unsigned short lK[3][64 * 64];
  __shared__ alignas(16) unsigned short lV[3][64 * 64];
  int tid = threadIdx.x;
  int wid = tid >> 6, lane = tid & 63;
  int g = lane >> 4, lr = lane & 15;
  int f = blockIdx.x;                  // 0..511
  int xcd = f & 7, rest = f >> 3;
  int bh = xcd + 8 * (rest & 3);       // 4 bh per XCD
  int qt = rest >> 2;                  // 0..15 (128-row q-tiles)
  int b = bh >> 4, h = bh & 15;
  const size_t koff = (size_t)bh * T_DIM * HD_DIM;   // q,k layout [bh][t][64]
  const size_t voff = (size_t)bh * HD_DIM * T_DIM;   // v^T layout [bh][64][T]

  int srow = tid >> 3;
  int gch  = (tid & 7) ^ (srow & 7);
  const unsigned short* ks0 = kb + koff + (size_t)srow * HD_DIM + gch * 8;
  const unsigned short* vs0 = vt + voff + (size_t)srow * T_DIM + gch * 8;

#define STAGE_TILE(buf, kofs, vofs)                                            \
  do {                                                                         \
    gload_lds16(ks0 + (kofs),                 lK[buf] + wid * 512);            \
    gload_lds16(ks0 + (kofs) + 32 * HD_DIM,   lK[buf] + 2048 + wid * 512);     \
    gload_lds16(vs0 + (vofs),                 lV[buf] + wid * 512);            \
    gload_lds16(vs0 + (vofs) + (size_t)32 * T_DIM, lV[buf] + 2048 + wid * 512);\
  } while (0)

  // Q fragments (32 q per wave, q = lr within each qa half), QS folded in
  bf16x8 qf[2][2];
  {
    const float QS = 0.125f * 1.44269504f;
#pragma unroll
    for (int qa = 0; qa < 2; ++qa) {
      int qrow = qt * 128 + wid * 32 + qa * 16 + lr;
#pragma unroll
      for (int ks = 0; ks < 2; ++ks) {
        bf16x8 raw = *(const bf16x8*)(qb + koff + (size_t)qrow * HD_DIM + ks * 32 + g * 8);
#pragma unroll
        for (int j = 0; j < 8; ++j) qf[qa][ks][j] = (__bf16)((float)raw[j] * QS);
      }
    }
  }

  bf16x8 onesf;
#pragma unroll
  for (int j = 0; j < 8; ++j) onesf[j] = (__bf16)1.0f;

  f32x4 accO[2][4] = {};   // accO[qa][df]: O^T[d=df*16+g*4+r][q=lr]
  f32x4 accS[2] = {};      // accS[qa][*]: rowsum for q=lr (rows identical)

  const int NT = T_DIM / 64;  // 32
  STAGE_TILE(0, 0, 0);        // prologue: tile 0

#define PROCESS(BUF, NBUF, TT, LAST)                                           \
  do {                                                                         \
    if (!(LAST)) {                                                             \
      size_t s1 = (size_t)((TT) + 1) * 64;                                     \
      STAGE_TILE(NBUF, s1 * HD_DIM, s1);                                       \
      asm volatile("s_waitcnt vmcnt(4)" ::: "memory");                         \
    } else {                                                                   \
      asm volatile("s_waitcnt vmcnt(0)" ::: "memory");                         \
    }                                                                          \
    __builtin_amdgcn_s_barrier();                                              \
    __builtin_amdgcn_sched_barrier(0);                                         \
    const unsigned short* Kc = lK[BUF];                                        \
    const unsigned short* Vc = lV[BUF];                                        \
    f32x4 s4[2][4];                                                            \
    __builtin_amdgcn_s_setprio(1);                                             \
    _Pragma("unroll")                                                          \
    for (int cf = 0; cf < 4; ++cf) {                                           \
      int row = cf * 16 + lr;                                                  \
      int sw = (row & 7) << 3;                                                 \
      bf16x8 k0 = *(const bf16x8*)(Kc + row * 64 + ((g * 8) ^ sw));            \
      bf16x8 k1 = *(const bf16x8*)(Kc + row * 64 + ((32 + g * 8) ^ sw));       \
      _Pragma("unroll")                                                        \
      for (int qa = 0; qa < 2; ++qa) {                                         \
        f32x4 s = {-8.0f, -8.0f, -8.0f, -8.0f};                                \
        s = __builtin_amdgcn_mfma_f32_16x16x32_bf16(k0, qf[qa][0], s, 0, 0, 0);\
        s = __builtin_amdgcn_mfma_f32_16x16x32_bf16(k1, qf[qa][1], s, 0, 0, 0);\
        s4[qa][cf] = s;                                                        \
      }                                                                        \
    }                                                                          \
    __builtin_amdgcn_s_setprio(0);                                             \
    bf16x8 pf[2][2];                                                           \
    _Pragma("unroll")                                                          \
    for (int qa = 0; qa < 2; ++qa)                                             \
      _Pragma("unroll")                                                        \
      for (int j = 0; j < 8; ++j) {                                            \
        pf[qa][0][j] = (__bf16)__builtin_amdgcn_exp2f(s4[qa][(j >> 2)][j & 3]);\
        pf[qa][1][j] = (__bf16)__builtin_amdgcn_exp2f(s4[qa][2 + (j >> 2)][j & 3]);\
      }                                                                        \
    __builtin_amdgcn_s_setprio(1);                                             \
    _Pragma("unroll")                                                          \
    for (int ks = 0; ks < 2; ++ks) {                                           \
      _Pragma("unroll")                                                        \
      for (int qa = 0; qa < 2; ++qa)                                           \
        accS[qa] = __builtin_amdgcn_mfma_f32_16x16x32_bf16(onesf, pf[qa][ks], accS[qa], 0, 0, 0); \
      _Pragma("unroll")                                                        \
      for (int df = 0; df < 4; ++df) {                                         \
        int row = df * 16 + lr;                                                \
        int sw = (row & 7) << 3;                                               \
        bf16x8 vf = *(const bf16x8*)(Vc + row * 64 + ((ks * 32 + g * 8) ^ sw));\
        _Pragma("unroll")                                                      \
        for (int qa = 0; qa < 2; ++qa)                                         \
          accO[qa][df] = __builtin_amdgcn_mfma_f32_16x16x32_bf16(vf, pf[qa][ks], accO[qa][df], 0, 0, 0); \
      }                                                                        \
    }                                                                          \
    __builtin_amdgcn_s_setprio(0);                                             \
  } while (0)

  for (int t3 = 0; t3 < 30; t3 += 3) {
    PROCESS(0, 1, t3 + 0, false);
    PROCESS(1, 2, t3 + 1, false);
    PROCESS(2, 0, t3 + 2, false);
  }
  PROCESS(0, 1, 30, false);
  PROCESS(1, 2, 31, true);
#undef PROCESS
#undef STAGE_TILE

  // Epilogue: O^T regs -> LDS (stride 72, reuse lK) -> coalesced ctx stores
  __syncthreads();
  unsigned short* sc = (unsigned short*)lK + wid * (32 * 72);
  float invl[2];
  invl[0] = 1.0f / accS[0][0];
  invl[1] = 1.0f / accS[1][0];
#pragma unroll
  for (int qa = 0; qa < 2; ++qa)
#pragma unroll
    for (int df = 0; df < 4; ++df)
#pragma unroll
      for (int r = 0; r < 4; ++r)
        sc[(qa * 16 + lr) * 72 + df * 16 + g * 4 + r] =
            f2bf(accO[qa][df][r] * invl[qa]);
  __syncthreads();
#pragma unroll
  for (int i = 0; i < 4; ++i) {
    int idx = i * 64 + lane;
    int row = idx >> 3, ch = idx & 7;
    u16x8 v8 = *(const u16x8*)(sc + row * 72 + ch * 8);
    int t = qt * 128 + wid * 32 + row;
    *(u16x8*)(&ctx[((size_t)t * B_DIM + b) * E_DIM + h * HD_DIM + ch * 8]) = v8;
  }
}

// ---------------- launcher ----------------
extern "C" void kernel_launch(void* const* d_in, const int* in_sizes, int n_in,
                              void* d_out, int out_size, void* d_ws, size_t ws_size,
                              hipStream_t stream) {
  const float* query = (const float*)d_in[0];
  const float* gamma = (const float*)d_in[1];
  const float* beta  = (const float*)d_in[2];
  const float* w_in  = (const float*)d_in[3];
  const float* w_out = (const float*)d_in[4];
  float* out = (float*)d_out;

  unsigned short* ws    = (unsigned short*)d_ws;
  unsigned short* ln    = ws;                                 // 8 MB
  unsigned short* winb  = ln + (size_t)M_DIM * E_DIM;         // 6 MB
  unsigned short* woutb = winb + (size_t)3 * E_DIM * E_DIM;   // 2 MB
  unsigned short* qkv   = woutb + (size_t)E_DIM * E_DIM;      // 24 MB

  unsigned short* qbuf = qkv;
  unsigned short* kbuf = qkv + (size_t)BH_DIM * T_DIM * HD_DIM;
  unsigned short* vbuf = kbuf + (size_t)BH_DIM * T_DIM * HD_DIM;
  unsigned short* vtb  = ln;    // reuse: ln consumed by GEMM0 before transpose
  unsigned short* ctx  = vbuf;  // reuse: vbuf consumed by transpose before attn

  cast2_kernel<<<dim3(4096), dim3(256), 0, stream>>>(
      w_in, winb, 3 * E_DIM * E_DIM / 4, w_out, woutb, E_DIM * E_DIM / 4);
  ln_kernel<<<dim3(M_DIM), dim3(256), 0, stream>>>(query, gamma, beta, ln);
  gemm0_kernel<<<dim3(3 * E_DIM / 128, M_DIM / 128), dim3(256), 0, stream>>>(
      ln, winb, qkv);
  transpose_v_kernel<<<dim3(T_DIM / 64, BH_DIM), dim3(256), 0, stream>>>(vbuf, vtb);
  attn_kernel<<<dim3(512), dim3(256), 0, stream>>>(qbuf, kbuf, vtb, ctx);
  gemm1_kernel<<<dim3(E_DIM / 64, M_DIM / 128), dim3(256), 0, stream>>>(
      ctx, woutb, query, out);
}